// Round 15
// baseline (65.959 us; speedup 1.0000x reference)
//
#include <hip/hip_runtime.h>

// 5-level wavedec (filter len 8, pywt 'symmetric'), 4096 rows of 8192 f32.
// Lengths: 8192 -> 4099 -> 2053 -> 1030 -> 518 -> 262
// Out: approx(262) @0, d5(262), d4(518), d3(1030), d2(2053), d1(4099).
//
// R15 = R14 + full input row staged into LDS first (reg-staged copy:
// 8x float4 loads -> 8x float4 ds_writes per thread, ONE global-latency
// exposure per block, overlapped across 3 resident blocks/CU). All 5
// levels then run at LDS latency (~120cy), hideable by 3 waves/SIMD.
// LDS reuse keeps footprint 48.4 KB: a2/a4 overwrite dead x-stage,
// a3 overwrites a1. Inter-level barriers are lgkmcnt-only (R14).

static constexpr int ROWS = 4096;
static constexpr int N0 = 8192;
static constexpr int L1n = 4099, L2n = 2053, L3n = 1030, L4n = 518, L5n = 262;
static constexpr size_t OFF_D5 = 1073152u;
static constexpr size_t OFF_D4 = 2146304u;
static constexpr size_t OFF_D3 = 4268032u;
static constexpr size_t OFF_D2 = 8486912u;
static constexpr size_t OFF_D1 = 16896000u;

// Barrier ordering LDS only (no vmcnt drain of global d-stores).
__device__ __forceinline__ void barrier_lds() {
    asm volatile("s_waitcnt lgkmcnt(0)\n\ts_barrier" ::: "memory");
}

__device__ __forceinline__ float refl_load(const float* __restrict__ s, int idx, int n) {
    int i = (idx < 0) ? (-1 - idx) : ((idx >= n) ? (2 * n - 1 - idx) : idx);
    return s[i];
}

// Clamped 16-float window load for group j: w[t] = src[8j-6+t]
template <int N>
__device__ __forceinline__ void load_window(const float* __restrict__ src,
                                            int j, float* __restrict__ w) {
    constexpr int jmax = (N - 10) >> 3;
    const int jb = j < 1 ? 1 : (j > jmax ? jmax : j);
    const float2* __restrict__ s2 = reinterpret_cast<const float2*>(src) + (4 * jb - 3);
#pragma unroll
    for (int t = 0; t < 8; ++t) {
        const float2 v = s2[t];
        w[2 * t] = v.x; w[2 * t + 1] = v.y;
    }
}

// Branchy symmetric-reflect path for edge / partial groups.
template <int N, int M>
__device__ __forceinline__ void edge_group(
    const float* __restrict__ src,
    const float* __restrict__ h, const float* __restrict__ g,
    float* __restrict__ adst, float* __restrict__ ddst, int j)
{
#pragma unroll 4
    for (int r = 0; r < 4; ++r) {
        const int pos = 4 * j + r;
        if (pos >= M) break;
        const int s0 = 2 * pos + 1;
        float a = 0.f, d = 0.f;
#pragma unroll
        for (int q = 0; q < 8; ++q) {
            const float v = refl_load(src, s0 - q, N);
            a = fmaf(h[q], v, a);
            d = fmaf(g[q], v, d);
        }
        ddst[pos] = d;
        adst[pos] = a;
    }
}

// One DWT level, NITER windows loaded upfront (all sources now LDS).
template <int N, int M, int NITER>
__device__ __forceinline__ void dwt_level(
    const float* __restrict__ src,
    const float* __restrict__ h, const float* __restrict__ g,
    float* __restrict__ adst, float* __restrict__ ddst, int tid)
{
    constexpr int ngroups = (M + 3) >> 2;
    constexpr int jmax = (N - 10) >> 3;
    constexpr int rem = ngroups - NITER * 256;       // leftover (edge) groups
    constexpr bool full = (NITER * 256 <= ngroups);  // all t-slots valid

    float w[NITER][16];
#pragma unroll
    for (int t = 0; t < NITER; ++t) {
        const int j = tid + t * 256;
        if (full || j < ngroups)
            load_window<N>(src, j, &w[t][0]);
    }
    __builtin_amdgcn_sched_barrier(0);   // pin: loads issued before compute

#pragma unroll
    for (int t = 0; t < NITER; ++t) {
        const int j = tid + t * 256;
        if (!full && j >= ngroups) break;
        const int p0 = 4 * j;
        if (j >= 1 && j <= jmax && p0 + 3 < M) {
            float aa[4], dd[4];
#pragma unroll
            for (int r = 0; r < 4; ++r) {
                float a = 0.f, d = 0.f;
#pragma unroll
                for (int q = 0; q < 8; ++q) {
                    const float v = w[t][2 * r + 7 - q];   // src[2(p0+r)+1-q]
                    a = fmaf(h[q], v, a);
                    d = fmaf(g[q], v, d);
                }
                aa[r] = a; dd[r] = d;
            }
#pragma unroll
            for (int r = 0; r < 4; ++r) ddst[p0 + r] = dd[r];
#pragma unroll
            for (int r = 0; r < 4; ++r) adst[p0 + r] = aa[r];
        } else {
            edge_group<N, M>(src, h, g, adst, ddst, j);
        }
    }
    if constexpr (rem > 0) {
        if (tid < rem)
            edge_group<N, M>(src, h, g, adst, ddst, NITER * 256 + tid);
    }
}

__global__ __launch_bounds__(256, 3)
void wavedec5_kernel(const float* __restrict__ x,
                     const float* __restrict__ dlo,
                     const float* __restrict__ dhi,
                     float* __restrict__ out)
{
    __shared__ __align__(16) float stage[N0];    // x; later a2 @0, a4 @4096
    __shared__ __align__(16) float bufA[4100];   // a1; later a3

    const int row = blockIdx.x;
    const int tid = threadIdx.x;

    float h[8], g[8];
#pragma unroll
    for (int i = 0; i < 8; ++i) { h[i] = dlo[i]; g[i] = dhi[i]; }

    const float* __restrict__ xr = x + (size_t)row * N0;

    // ---- stage the row into LDS (coalesced, one latency exposure) ----
    {
        const float4* __restrict__ xg = reinterpret_cast<const float4*>(xr);
        float4 v[8];
#pragma unroll
        for (int i = 0; i < 8; ++i) v[i] = xg[tid + i * 256];
        __builtin_amdgcn_sched_barrier(0);       // all 8 loads in flight first
        float4* __restrict__ sg = reinterpret_cast<float4*>(stage);
#pragma unroll
        for (int i = 0; i < 8; ++i) sg[tid + i * 256] = v[i];
    }
    barrier_lds();

    float* __restrict__ a2p = stage;             // 2053 fl, overwrites dead x
    float* __restrict__ a4p = stage + 4096;      // 518 fl, x area (16B-aligned)

    // L1: stage(x) -> bufA(a1), d1 -> global
    dwt_level<N0, L1n, 4>(stage, h, g, bufA,
                          out + OFF_D1 + (size_t)row * L1n, tid);
    barrier_lds();
    // L2: bufA(a1) -> a2p, d2 -> global  (x dead after L1 barrier)
    dwt_level<L1n, L2n, 2>(bufA, h, g, a2p,
                           out + OFF_D2 + (size_t)row * L2n, tid);
    barrier_lds();
    // L3: a2p -> bufA(a3, overwrites dead a1), d3 -> global
    dwt_level<L2n, L3n, 1>(a2p, h, g, bufA,
                           out + OFF_D3 + (size_t)row * L3n, tid);
    barrier_lds();
    // L4: bufA(a3) -> a4p, d4 -> global  (disjoint from a2p[0..2052])
    dwt_level<L3n, L4n, 1>(bufA, h, g, a4p,
                           out + OFF_D4 + (size_t)row * L4n, tid);
    barrier_lds();
    // L5: a4p -> approx & d5 straight to global
    dwt_level<L4n, L5n, 1>(a4p, h, g,
                           out + (size_t)row * L5n,
                           out + OFF_D5 + (size_t)row * L5n, tid);
}

extern "C" void kernel_launch(void* const* d_in, const int* in_sizes, int n_in,
                              void* d_out, int out_size, void* d_ws, size_t ws_size,
                              hipStream_t stream) {
    const float* x   = (const float*)d_in[0];
    const float* dlo = (const float*)d_in[1];
    const float* dhi = (const float*)d_in[2];
    float* out = (float*)d_out;
    wavedec5_kernel<<<ROWS, 256, 0, stream>>>(x, dlo, dhi, out);
}